// Round 16
// baseline (152.539 us; speedup 1.0000x reference)
//
#include <hip/hip_runtime.h>
#include <hip/hip_bf16.h>
#include <math.h>

#define BB 2
#define CC 128
#define CHH 64
#define DD 16
#define NN 4096   // 16*16*16
#define SP 256    // 16*16
#define KTOT 3456 // 27*128
#define NKS 16    // key slices for split-K attention (256 keys each)

typedef float  f32x4 __attribute__((ext_vector_type(4)));
typedef short  s16x4 __attribute__((ext_vector_type(4)));
typedef short  s16x8 __attribute__((ext_vector_type(8)));

static __device__ __forceinline__ unsigned short f2bf(float x) {
    __hip_bfloat16 h = __float2bfloat16(x);
    return __builtin_bit_cast(unsigned short, h);
}

// ---------------- K0: weight prep ----------------
__global__ __launch_bounds__(256) void k_prep(const float* __restrict__ c1w, const float* __restrict__ c2w,
                                              const float* __restrict__ bg, const float* __restrict__ bbeta,
                                              const float* __restrict__ bm, const float* __restrict__ bv,
                                              const float* __restrict__ c2b,
                                              const float* __restrict__ qw, const float* __restrict__ kw,
                                              const float* __restrict__ vw,
                                              unsigned short* __restrict__ Wb,
                                              unsigned short* __restrict__ w2p,
                                              float* __restrict__ b2p,
                                              unsigned short* __restrict__ qwb,
                                              unsigned short* __restrict__ kwb,
                                              unsigned short* __restrict__ vwb) {
    int idx = blockIdx.x * 256 + threadIdx.x;
    for (int e = idx; e < CHH * KTOT; e += gridDim.x * 256) {
        int h = e / KTOT, rem = e % KTOT, tap = rem >> 7, c = rem & 127;
        Wb[e] = f2bf(c1w[(h * CC + c) * 27 + tap]);
    }
    for (int e = idx; e < CC * CC; e += gridDim.x * 256) {
        qwb[e] = f2bf(qw[e]);
        kwb[e] = f2bf(kw[e]);
        vwb[e] = f2bf(vw[e]);
    }
    for (int e = idx; e < CC * CHH; e += gridDim.x * 256) {
        int h = e & 63;
        float iv = rsqrtf(bv[h] + 1e-5f);
        w2p[e] = f2bf(c2w[e] * bg[h] * iv);
    }
    if (idx < CC) {
        float s = c2b[idx];
        for (int h = 0; h < CHH; h++) {
            float iv = rsqrtf(bv[h] + 1e-5f);
            s += c2w[idx * CHH + h] * (bbeta[h] - bm[h] * bg[h] * iv);
        }
        b2p[idx] = s;
    }
}

// ---------------- K1: pooled = mean over spatial of (mri+pet), per (b,c) ----------------
__global__ __launch_bounds__(256) void k_pool(const float* __restrict__ mri,
                                              const float* __restrict__ pet,
                                              float* __restrict__ pooled) {
    int bc = blockIdx.x;
    const float* m = mri + (size_t)bc * NN;
    const float* p = pet + (size_t)bc * NN;
    float s = 0.f;
    for (int i = threadIdx.x; i < NN; i += 256) s += m[i] + p[i];
    __shared__ float red[256];
    red[threadIdx.x] = s;
    __syncthreads();
    for (int off = 128; off > 0; off >>= 1) {
        if (threadIdx.x < off) red[threadIdx.x] += red[threadIdx.x + off];
        __syncthreads();
    }
    if (threadIdx.x == 0) pooled[bc] = red[0] * (1.0f / NN);
}

// ---------------- K2: channel attention MLP -> cw (B,C) ----------------
__global__ __launch_bounds__(128) void k_cw(const float* __restrict__ pooled,
                                            const float* __restrict__ w1, const float* __restrict__ b1,
                                            const float* __restrict__ w2, const float* __restrict__ b2,
                                            float* __restrict__ cw) {
    __shared__ float pl[BB * CC];
    __shared__ float tl[BB * CHH];
    int t = threadIdx.x;
    pl[t] = pooled[t];
    pl[t + 128] = pooled[t + 128];
    __syncthreads();
    {
        int b = t >> 6, h = t & 63;
        float acc = b1[h];
        for (int c = 0; c < CC; c++) acc += pl[b * CC + c] * w1[h * CC + c];
        tl[b * CHH + h] = fmaxf(acc, 0.f);
    }
    __syncthreads();
    for (int b = 0; b < BB; b++) {
        float acc = b2[t];
        for (int h = 0; h < CHH; h++) acc += tl[b * CHH + h] * w2[t * CHH + h];
        cw[b * CC + t] = 1.f / (1.f + __expf(-acc));
    }
}

// ---------------- K3: Q/K/V 1x1 convs via MFMA; bf16 outputs ----------------
// Qt, Kt: (b, n, c) bf16 ; Vc: (b, c, n) bf16   (replay-proven layouts)
__global__ __launch_bounds__(256) void k_qkv(const float* __restrict__ mri, const float* __restrict__ pet,
                                             const float* __restrict__ cw,
                                             const unsigned short* __restrict__ qwb, const float* __restrict__ qb,
                                             const unsigned short* __restrict__ kwb, const float* __restrict__ kb,
                                             const unsigned short* __restrict__ vwb, const float* __restrict__ vb,
                                             unsigned short* __restrict__ Qt, unsigned short* __restrict__ Kt,
                                             unsigned short* __restrict__ Vc) {
    __shared__ unsigned short am[32][136];
    __shared__ unsigned short ap[32][136];
    int blk = blockIdx.x;          // 256
    int b = blk >> 7;
    int n0 = (blk & 127) * 32;
    int t = threadIdx.x;
    for (int e = t; e < 64 * 32; e += 256) {
        int c2 = (e >> 5) << 1, j = e & 31;
        float cw0 = cw[b * CC + c2], cw1 = cw[b * CC + c2 + 1];
        size_t g0 = (size_t)(b * CC + c2) * NN + n0 + j;
        unsigned int pm = (unsigned int)f2bf(mri[g0] * cw0) | ((unsigned int)f2bf(mri[g0 + NN] * cw1) << 16);
        unsigned int pp = (unsigned int)f2bf(pet[g0] * cw0) | ((unsigned int)f2bf(pet[g0 + NN] * cw1) << 16);
        *(unsigned int*)&am[j][c2] = pm;
        *(unsigned int*)&ap[j][c2] = pp;
    }
    __syncthreads();
    int wv = t >> 6, lane = t & 63;
    int lrow = lane & 15, lg = lane >> 4;
    int o0 = wv * 32;

    s16x8 bf[2][4];
    s16x8 wf[2][4];
    f32x4 acc[2][2];

#define QKV_MAT(WPTR, BIAS, ACT)                                                            \
    {                                                                                       \
        _Pragma("unroll")                                                                   \
        for (int nt = 0; nt < 2; nt++)                                                      \
            _Pragma("unroll")                                                               \
            for (int ks = 0; ks < 4; ks++)                                                  \
                bf[nt][ks] = *(const s16x8*)&ACT[nt * 16 + lrow][ks * 32 + lg * 8];         \
        _Pragma("unroll")                                                                   \
        for (int m = 0; m < 2; m++)                                                         \
            _Pragma("unroll")                                                               \
            for (int ks = 0; ks < 4; ks++)                                                  \
                wf[m][ks] = *(const s16x8*)&WPTR[(size_t)(o0 + m * 16 + lrow) * CC + ks * 32 + lg * 8]; \
        _Pragma("unroll")                                                                   \
        for (int m = 0; m < 2; m++) {                                                       \
            float b0 = BIAS[o0 + m * 16 + lg * 4 + 0];                                      \
            float b1 = BIAS[o0 + m * 16 + lg * 4 + 1];                                      \
            float b2v = BIAS[o0 + m * 16 + lg * 4 + 2];                                     \
            float b3 = BIAS[o0 + m * 16 + lg * 4 + 3];                                      \
            _Pragma("unroll")                                                               \
            for (int nt = 0; nt < 2; nt++) {                                                \
                acc[m][nt] = (f32x4){b0, b1, b2v, b3};                                      \
                _Pragma("unroll")                                                           \
                for (int ks = 0; ks < 4; ks++)                                              \
                    acc[m][nt] = __builtin_amdgcn_mfma_f32_16x16x32_bf16(wf[m][ks], bf[nt][ks], acc[m][nt], 0, 0, 0); \
            }                                                                               \
        }                                                                                   \
    }

    QKV_MAT(qwb, qb, am);
#pragma unroll
    for (int m = 0; m < 2; m++)
#pragma unroll
        for (int nt = 0; nt < 2; nt++) {
            s16x4 q4;
#pragma unroll
            for (int r = 0; r < 4; r++) q4[r] = (short)f2bf(acc[m][nt][r]);
            *(s16x4*)&Qt[((size_t)b * NN + n0 + nt * 16 + lrow) * CC + o0 + m * 16 + lg * 4] = q4;
        }
    QKV_MAT(kwb, kb, ap);
#pragma unroll
    for (int m = 0; m < 2; m++)
#pragma unroll
        for (int nt = 0; nt < 2; nt++) {
            s16x4 k4;
#pragma unroll
            for (int r = 0; r < 4; r++) k4[r] = (short)f2bf(acc[m][nt][r]);
            *(s16x4*)&Kt[((size_t)b * NN + n0 + nt * 16 + lrow) * CC + o0 + m * 16 + lg * 4] = k4;
        }
    QKV_MAT(vwb, vb, ap);
#pragma unroll
    for (int m = 0; m < 2; m++)
#pragma unroll
        for (int nt = 0; nt < 2; nt++)
#pragma unroll
            for (int r = 0; r < 4; r++)
                Vc[((size_t)b * CC + o0 + m * 16 + lg * 4 + r) * NN + n0 + nt * 16 + lrow] =
                    (unsigned short)f2bf(acc[m][nt][r]);
#undef QKV_MAT
}

// ---------------- K4: MFMA attention, LDS-staged split-K v4 ----------------
// grid 512 = ks(16 slices of 256 keys) x qc(16) x b(2); 512 thr = 8 waves.
// 2 blocks/CU -> barrier drains overlap with the co-resident block's compute
// (1-block/CU was the round-13/15 stall). Key-permuted V: PV A-frag = one
// bank-balanced ds_read_b128. Total staging bytes unchanged vs NKS=8.
#define QW 32
__global__ __launch_bounds__(512) void k_attn(const unsigned short* __restrict__ Qt,
                                              const unsigned short* __restrict__ Kt,
                                              const unsigned short* __restrict__ Vc,
                                              float* __restrict__ Opart) {
    __shared__ unsigned short Ks[2][32][136];   // 17408 B
    __shared__ unsigned short Vs[2][128][40];   // 20480 B (cols 0..31 = permuted keys)
    int bid = blockIdx.x;          // 0..511
    int ks = bid & 15;             // key slice (XCD = bid%8; 2 slices per XCD)
    int r = bid >> 4;              // 0..31
    int qc = r >> 1;               // 0..15
    int b = r & 1;
    int t = threadIdx.x;           // 0..511
    int wv = t >> 6;               // 0..7
    int lane = t & 63;
    int lrow = lane & 15;
    int lg = lane >> 4;
    int q0 = qc * 256 + wv * 32;

    const unsigned short* Qb = Qt + (size_t)b * NN * CC;
    const unsigned short* Kb = Kt + (size_t)b * NN * CC;
    const unsigned short* Vb = Vc + (size_t)b * CC * NN;

    // stage (512 thr): K = 512 b128 units (1/thread); V = 1024 b64 units
    // (2/thread), key k -> in-row pos 8*((k&15)>>2) + (k&3) + 4*(k>>4).
#define STAGE(BUF, K0)                                                                      \
    {                                                                                       \
        {                                                                                   \
            int row = t >> 4, seg = t & 15;                                                 \
            *(s16x8*)&Ks[BUF][row][seg * 8] =                                               \
                *(const s16x8*)(Kb + (size_t)((K0) + row) * CC + seg * 8);                  \
        }                                                                                   \
        _Pragma("unroll")                                                                   \
        for (int e2 = 0; e2 < 2; e2++) {                                                    \
            int e = t + e2 * 512; int c = e >> 3, m = e & 7;                                \
            *(s16x4*)&Vs[BUF][c][8 * (m & 3) + 4 * (m >> 2)] =                              \
                *(const s16x4*)(Vb + (size_t)c * NN + (K0) + 4 * m);                        \
        }                                                                                   \
    }

    s16x8 qf[2][4];
#pragma unroll
    for (int qt = 0; qt < 2; qt++)
#pragma unroll
        for (int cc = 0; cc < 4; cc++)
            qf[qt][cc] = *(const s16x8*)(Qb + (size_t)(q0 + qt * 16 + lrow) * CC + cc * 32 + lg * 8);

    f32x4 acc[2][8];
#pragma unroll
    for (int qt = 0; qt < 2; qt++)
#pragma unroll
        for (int ct = 0; ct < 8; ct++) acc[qt][ct] = (f32x4){0.f, 0.f, 0.f, 0.f};

    int kbase = ks * 256;
    STAGE(0, kbase);
#pragma unroll 1
    for (int i = 0; i < 8; i++) {
        __syncthreads();
        if (i + 1 < 8) STAGE((i + 1) & 1, kbase + (i + 1) * 32);
        int cur = i & 1;
        f32x4 sc[2][2];
#pragma unroll
        for (int kt = 0; kt < 2; kt++) {
            s16x8 kf[4];
#pragma unroll
            for (int cc = 0; cc < 4; cc++)
                kf[cc] = *(const s16x8*)&Ks[cur][kt * 16 + lrow][cc * 32 + lg * 8];
#pragma unroll
            for (int qt = 0; qt < 2; qt++) {
                f32x4 a = (f32x4){0.f, 0.f, 0.f, 0.f};
#pragma unroll
                for (int cc = 0; cc < 4; cc++)
                    a = __builtin_amdgcn_mfma_f32_16x16x32_bf16(kf[cc], qf[qt][cc], a, 0, 0, 0);
                sc[qt][kt] = a;
            }
        }
        s16x8 pf[2];
#pragma unroll
        for (int qt = 0; qt < 2; qt++) {
#pragma unroll
            for (int kt = 0; kt < 2; kt++) {
                f32x4 s = sc[qt][kt];
                float m = fmaxf(fmaxf(s[0], s[1]), fmaxf(s[2], s[3]));
                m = fmaxf(m, __shfl_xor(m, 16));
                m = fmaxf(m, __shfl_xor(m, 32));
                float e0 = __expf(s[0] - m), e1 = __expf(s[1] - m);
                float e2 = __expf(s[2] - m), e3 = __expf(s[3] - m);
                float sum = e0 + e1 + e2 + e3;
                sum += __shfl_xor(sum, 16);
                sum += __shfl_xor(sum, 32);
                float inv = 1.0f / sum;
                pf[qt][kt * 4 + 0] = (short)f2bf(e0 * inv);
                pf[qt][kt * 4 + 1] = (short)f2bf(e1 * inv);
                pf[qt][kt * 4 + 2] = (short)f2bf(e2 * inv);
                pf[qt][kt * 4 + 3] = (short)f2bf(e3 * inv);
            }
        }
        // PV: one bank-balanced b128 per ct (permuted layout = A-frag order)
#pragma unroll
        for (int ct = 0; ct < 8; ct++) {
            s16x8 vf = *(const s16x8*)&Vs[cur][ct * 16 + lrow][8 * lg];
            acc[0][ct] = __builtin_amdgcn_mfma_f32_16x16x32_bf16(vf, pf[0], acc[0][ct], 0, 0, 0);
            acc[1][ct] = __builtin_amdgcn_mfma_f32_16x16x32_bf16(vf, pf[1], acc[1][ct], 0, 0, 0);
        }
    }
#undef STAGE
    float* Op = Opart + ((size_t)(ks * BB + b) * NN) * CC;
#pragma unroll
    for (int qt = 0; qt < 2; qt++)
#pragma unroll
        for (int ct = 0; ct < 8; ct++)
            *(f32x4*)&Op[(size_t)(q0 + qt * 16 + lrow) * CC + ct * 16 + lg * 4] = acc[qt][ct];
}

// ---------------- K4b: combine 16 slice-partials + mri*cw -> Xb (b,n,c) bf16 ----------------
__global__ __launch_bounds__(256) void k_comb(const float* __restrict__ Opart,
                                              const float* __restrict__ mri, const float* __restrict__ cw,
                                              unsigned short* __restrict__ Xb) {
    __shared__ float tl[128][33];
    __shared__ float cws[128];
    int bid = blockIdx.x;             // 256 = b*128 + nb
    int b = bid >> 7, n0 = (bid & 127) * 32;
    int t = threadIdx.x;
    if (t < 128) cws[t] = cw[b * CC + t];
    {
        int c = t >> 1, half = t & 1;
        const float* src = mri + (size_t)(b * CC + c) * NN + n0 + half * 16;
#pragma unroll
        for (int j = 0; j < 4; j++) {
            f32x4 v = *(const f32x4*)(src + j * 4);
            tl[c][half * 16 + j * 4 + 0] = v[0];
            tl[c][half * 16 + j * 4 + 1] = v[1];
            tl[c][half * 16 + j * 4 + 2] = v[2];
            tl[c][half * 16 + j * 4 + 3] = v[3];
        }
    }
    __syncthreads();
    {
        int n = t >> 3, c0 = (t & 7) * 16;
        size_t rowoff = (size_t)(n0 + n) * CC + c0;
        s16x8 o0v, o1v;
#pragma unroll
        for (int ci = 0; ci < 4; ci++) {
            f32x4 s = (f32x4){0.f, 0.f, 0.f, 0.f};
#pragma unroll
            for (int ks = 0; ks < NKS; ks++) {
                f32x4 p = *(const f32x4*)&Opart[((size_t)(ks * BB + b) * NN) * CC + rowoff + ci * 4];
                s[0] += p[0]; s[1] += p[1]; s[2] += p[2]; s[3] += p[3];
            }
#pragma unroll
            for (int j = 0; j < 4; j++) {
                int c = c0 + ci * 4 + j;
                float v = s[j] + tl[c][n] * cws[c];
                if (ci < 2) o0v[ci * 4 + j] = (short)f2bf(v);
                else        o1v[(ci - 2) * 4 + j] = (short)f2bf(v);
            }
        }
        unsigned short* dst = Xb + ((size_t)b * NN + n0 + n) * CC + c0;
        *(s16x8*)dst = o0v;
        *(s16x8*)(dst + 8) = o1v;
    }
}

// ---------------- K4-fallback: round-10 attention (if ws too small for Opart) ----------------
__global__ __launch_bounds__(512) void k_attn_fb(const unsigned short* __restrict__ Qt,
                                                 const unsigned short* __restrict__ Kt,
                                                 const unsigned short* __restrict__ Vc,
                                                 const float* __restrict__ mri, const float* __restrict__ cw,
                                                 unsigned short* __restrict__ Xb) {
    __shared__ float Op[8][16][68];
    int bid = blockIdx.x;
    int lid = (bid & 7) * 32 + (bid >> 3);
    int b = lid >> 7;
    int q0 = (lid & 127) * QW;
    int t = threadIdx.x;
    int wv = t >> 6;
    int lane = t & 63;
    int lrow = lane & 15;
    int lg = lane >> 4;

    const unsigned short* Qb = Qt + (size_t)b * NN * CC;
    const unsigned short* Kb = Kt + (size_t)b * NN * CC;
    const unsigned short* Vb = Vc + (size_t)b * CC * NN;

    s16x8 qf[2][4];
#pragma unroll
    for (int qt = 0; qt < 2; qt++)
#pragma unroll
        for (int cc = 0; cc < 4; cc++)
            qf[qt][cc] = *(const s16x8*)(Qb + (size_t)(q0 + qt * 16 + lrow) * CC + cc * 32 + lg * 8);

    f32x4 acc[2][8];
#pragma unroll
    for (int qt = 0; qt < 2; qt++)
#pragma unroll
        for (int ct = 0; ct < 8; ct++) acc[qt][ct] = (f32x4){0.f, 0.f, 0.f, 0.f};

    for (int kg = wv; kg < 128; kg += 8) {
        int k0 = kg * 32;
        f32x4 sc[2][2];
#pragma unroll
        for (int kt = 0; kt < 2; kt++) {
            s16x8 kf[4];
#pragma unroll
            for (int cc = 0; cc < 4; cc++)
                kf[cc] = *(const s16x8*)(Kb + (size_t)(k0 + kt * 16 + lrow) * CC + cc * 32 + lg * 8);
#pragma unroll
            for (int qt = 0; qt < 2; qt++) {
                f32x4 a = (f32x4){0.f, 0.f, 0.f, 0.f};
#pragma unroll
                for (int cc = 0; cc < 4; cc++)
                    a = __builtin_amdgcn_mfma_f32_16x16x32_bf16(kf[cc], qf[qt][cc], a, 0, 0, 0);
                sc[qt][kt] = a;
            }
        }
        s16x8 pf[2];
#pragma unroll
        for (int qt = 0; qt < 2; qt++) {
#pragma unroll
            for (int kt = 0; kt < 2; kt++) {
                f32x4 s = sc[qt][kt];
                float m = fmaxf(fmaxf(s[0], s[1]), fmaxf(s[2], s[3]));
                m = fmaxf(m, __shfl_xor(m, 16));
                m = fmaxf(m, __shfl_xor(m, 32));
                float e0 = __expf(s[0] - m), e1 = __expf(s[1] - m);
                float e2 = __expf(s[2] - m), e3 = __expf(s[3] - m);
                float sum = e0 + e1 + e2 + e3;
                sum += __shfl_xor(sum, 16);
                sum += __shfl_xor(sum, 32);
                float inv = 1.0f / sum;
                pf[qt][kt * 4 + 0] = (short)f2bf(e0 * inv);
                pf[qt][kt * 4 + 1] = (short)f2bf(e1 * inv);
                pf[qt][kt * 4 + 2] = (short)f2bf(e2 * inv);
                pf[qt][kt * 4 + 3] = (short)f2bf(e3 * inv);
            }
        }
#pragma unroll
        for (int ct = 0; ct < 8; ct++) {
            const unsigned short* vp = Vb + (size_t)(ct * 16 + lrow) * NN + k0 + 4 * lg;
            s16x4 v0 = *(const s16x4*)vp;
            s16x4 v1 = *(const s16x4*)(vp + 16);
            s16x8 vf = (s16x8){v0[0], v0[1], v0[2], v0[3], v1[0], v1[1], v1[2], v1[3]};
            acc[0][ct] = __builtin_amdgcn_mfma_f32_16x16x32_bf16(vf, pf[0], acc[0][ct], 0, 0, 0);
            acc[1][ct] = __builtin_amdgcn_mfma_f32_16x16x32_bf16(vf, pf[1], acc[1][ct], 0, 0, 0);
        }
    }
#pragma unroll
    for (int p = 0; p < 4; p++) {
        int qt = p >> 1, ch = p & 1;
#pragma unroll
        for (int ci = 0; ci < 4; ci++)
            *(f32x4*)&Op[wv][lrow][ci * 16 + lg * 4] = acc[qt][ch * 4 + ci];
        __syncthreads();
#pragma unroll
        for (int rep = 0; rep < 2; rep++) {
            int e = t + rep * 512;
            int cl = e & 63, q = e >> 6;
            int c = ch * 64 + cl;
            float s = 0.f;
#pragma unroll
            for (int w = 0; w < 8; w++) s += Op[w][q][cl];
            int n = q0 + qt * 16 + q;
            size_t gi = ((size_t)b * CC + c) * NN + n;
            Xb[((size_t)b * NN + n) * CC + c] = f2bf(s + mri[gi] * cw[b * CC + c]);
        }
        __syncthreads();
    }
}

// ---------------- K5: 3x3x3 conv, LDS-staged implicit-GEMM MFMA + bias + ReLU ----------------
__global__ __launch_bounds__(512) void k_conv3(const unsigned short* __restrict__ Xb,
                                               const unsigned short* __restrict__ Wb,
                                               const float* __restrict__ c1b,
                                               unsigned short* __restrict__ Yb) {
    __shared__ unsigned short Xs[3][4][18][136];  // 58752 B  (w shifted +1, OOB zero)
    __shared__ unsigned short Ws[2][64][136];     // 34816 B  (cols 0..127 used)
    int bid = blockIdx.x;             // 256 = b*128 + d*8 + hq
    int b = bid >> 7;
    int d = (bid >> 3) & 15;
    int hp = (bid & 7) * 2;
    int t = threadIdx.x;
    int wv = t >> 6;
    int lane = t & 63;
    int lrow = lane & 15, lg = lane >> 4;
    int mt = wv >> 1;        // ch tile 0..3
    int nt = wv & 1;         // h row 0..1

    const unsigned short* Xbase = Xb + (size_t)b * NN * CC;

    {
        unsigned short* xz = &Xs[0][0][0][0];
        const s16x8 z8 = (s16x8){0, 0, 0, 0, 0, 0, 0, 0};
        for (int e = t; e < (3 * 4 * 18 * 136) / 8; e += 512)
            *(s16x8*)(xz + e * 8) = z8;
    }
    __syncthreads();
    for (int e = t; e < 3 * 4 * 16 * 16; e += 512) {
        int seg = e & 15;
        int w = (e >> 4) & 15;
        int sh = (e >> 8) & 3;
        int sd = e >> 10;
        int dd2 = d - 1 + sd, hh2 = hp - 1 + sh;
        if ((unsigned)dd2 < 16u && (unsigned)hh2 < 16u) {
            int n = dd2 * 256 + hh2 * 16 + w;
            *(s16x8*)&Xs[sd][sh][w + 1][seg * 8] = *(const s16x8*)(Xbase + (size_t)n * CC + seg * 8);
        }
    }

#define WSTAGE(BUF, TAP)                                                       \
    for (int e = t; e < 1024; e += 512) {                                      \
        int row = e >> 4, seg = e & 15;                                        \
        *(s16x8*)&Ws[BUF][row][seg * 8] =                                      \
            *(const s16x8*)(Wb + (size_t)row * KTOT + (TAP) * 128 + seg * 8);  \
    }
    WSTAGE(0, 0);

    f32x4 acc = (f32x4){0.f, 0.f, 0.f, 0.f};
#pragma unroll 1
    for (int tap = 0; tap < 27; tap++) {
        __syncthreads();
        if (tap + 1 < 27) { WSTAGE((tap + 1) & 1, tap + 1); }
        int cur = tap & 1;
        int kd = tap / 9;
        int rem = tap - kd * 9;
        int kh = rem / 3;
        int kw = rem - kh * 3;
#pragma unroll
        for (int cc = 0; cc < 4; cc++) {
            s16x8 af = *(const s16x8*)&Ws[cur][mt * 16 + lrow][cc * 32 + lg * 8];
            s16x8 bfv = *(const s16x8*)&Xs[kd][nt + kh][lrow + kw][cc * 32 + lg * 8];
            acc = __builtin_amdgcn_mfma_f32_16x16x32_bf16(af, bfv, acc, 0, 0, 0);
        }
    }
#undef WSTAGE
    int ch0 = mt * 16 + lg * 4;
    int n = d * 256 + (hp + nt) * 16 + lrow;
    s16x4 yv;
#pragma unroll
    for (int r = 0; r < 4; r++) {
        float y = fmaxf(acc[r] + c1b[ch0 + r], 0.f);
        yv[r] = (short)f2bf(y);
    }
    *(s16x4*)&Yb[((size_t)b * NN + n) * CHH + ch0] = yv;
}

// ---------------- K6: final 1x1 conv (CH->C) via MFMA, BN pre-folded ----------------
__global__ __launch_bounds__(256) void k_out(const unsigned short* __restrict__ Yb,
                                             const unsigned short* __restrict__ w2p,
                                             const float* __restrict__ b2p,
                                             float* __restrict__ out) {
    int bid = blockIdx.x;    // 256
    int b = bid >> 7, n0 = (bid & 127) * 32;
    int t = threadIdx.x;
    int wv = t >> 6, lane = t & 63;
    int lrow = lane & 15, lg = lane >> 4;
    int o0 = wv * 32;

    f32x4 acc[2][2];
#pragma unroll
    for (int m = 0; m < 2; m++)
#pragma unroll
        for (int nt = 0; nt < 2; nt++) acc[m][nt] = (f32x4){0.f, 0.f, 0.f, 0.f};

#pragma unroll
    for (int ks = 0; ks < 2; ks++) {
        s16x8 a0 = *(const s16x8*)&w2p[(o0 + lrow) * CHH + ks * 32 + lg * 8];
        s16x8 a1 = *(const s16x8*)&w2p[(o0 + 16 + lrow) * CHH + ks * 32 + lg * 8];
        s16x8 f0 = *(const s16x8*)&Yb[((size_t)b * NN + n0 + lrow) * CHH + ks * 32 + lg * 8];
        s16x8 f1 = *(const s16x8*)&Yb[((size_t)b * NN + n0 + 16 + lrow) * CHH + ks * 32 + lg * 8];
        acc[0][0] = __builtin_amdgcn_mfma_f32_16x16x32_bf16(a0, f0, acc[0][0], 0, 0, 0);
        acc[0][1] = __builtin_amdgcn_mfma_f32_16x16x32_bf16(a0, f1, acc[0][1], 0, 0, 0);
        acc[1][0] = __builtin_amdgcn_mfma_f32_16x16x32_bf16(a1, f0, acc[1][0], 0, 0, 0);
        acc[1][1] = __builtin_amdgcn_mfma_f32_16x16x32_bf16(a1, f1, acc[1][1], 0, 0, 0);
    }
#pragma unroll
    for (int m = 0; m < 2; m++) {
#pragma unroll
        for (int r = 0; r < 4; r++) {
            int o = o0 + m * 16 + lg * 4 + r;
            float bias = b2p[o];
#pragma unroll
            for (int nt = 0; nt < 2; nt++) {
                int n = n0 + nt * 16 + lrow;
                out[((size_t)b * CC + o) * NN + n] = acc[m][nt][r] + bias;
            }
        }
    }
}

extern "C" void kernel_launch(void* const* d_in, const int* in_sizes, int n_in,
                              void* d_out, int out_size, void* d_ws, size_t ws_size,
                              hipStream_t stream) {
    const float* mri = (const float*)d_in[0];
    const float* pet = (const float*)d_in[1];
    const float* qw  = (const float*)d_in[2];
    const float* qb  = (const float*)d_in[3];
    const float* kw  = (const float*)d_in[4];
    const float* kb  = (const float*)d_in[5];
    const float* vw  = (const float*)d_in[6];
    const float* vb  = (const float*)d_in[7];
    const float* w1  = (const float*)d_in[8];
    const float* b1  = (const float*)d_in[9];
    const float* w2  = (const float*)d_in[10];
    const float* b2  = (const float*)d_in[11];
    const float* c1w = (const float*)d_in[12];
    const float* c1b = (const float*)d_in[13];
    const float* bg  = (const float*)d_in[14];
    const float* bbeta = (const float*)d_in[15];
    const float* bm  = (const float*)d_in[16];
    const float* bv  = (const float*)d_in[17];
    const float* c2w = (const float*)d_in[18];
    const float* c2b = (const float*)d_in[19];
    float* out = (float*)d_out;

    float* ws = (float*)d_ws;
    float* pooled = ws;                               // 256 f32
    float* cwb    = ws + 256;                         // 256 f32
    float* b2p    = ws + 512;                         // 128 f32
    unsigned short* Qt  = (unsigned short*)(ws + 1024);
    unsigned short* Kt  = Qt + (size_t)BB * NN * CC;
    unsigned short* Vc  = Kt + (size_t)BB * NN * CC;
    unsigned short* Xb  = Vc + (size_t)BB * NN * CC;  // (b,n,c) bf16
    unsigned short* Yb  = Xb + (size_t)BB * NN * CC;  // (b,n,h) bf16
    unsigned short* Wb  = Yb + (size_t)BB * NN * CHH; // 64*3456 bf16
    unsigned short* w2p = Wb + (size_t)CHH * KTOT;    // 128*64 bf16
    unsigned short* qwb = w2p + (size_t)CC * CHH;     // 128*128 bf16
    unsigned short* kwb = qwb + (size_t)CC * CC;
    unsigned short* vwb = kwb + (size_t)CC * CC;
    // 16B-align Opart
    size_t head_bytes = (size_t)((char*)(vwb + (size_t)CC * CC) - (char*)d_ws);
    head_bytes = (head_bytes + 15) & ~(size_t)15;
    float* Opart = (float*)((char*)d_ws + head_bytes);
    size_t opart_bytes = (size_t)NKS * BB * NN * CC * sizeof(float);   // 64 MB
    bool use_split = (head_bytes + opart_bytes) <= ws_size;

    k_prep<<<64, 256, 0, stream>>>(c1w, c2w, bg, bbeta, bm, bv, c2b, qw, kw, vw,
                                   Wb, w2p, b2p, qwb, kwb, vwb);
    k_pool<<<BB * CC, 256, 0, stream>>>(mri, pet, pooled);
    k_cw<<<1, 128, 0, stream>>>(pooled, w1, b1, w2, b2, cwb);
    k_qkv<<<BB * (NN / 32), 256, 0, stream>>>(mri, pet, cwb, qwb, qb, kwb, kb, vwb, vb, Qt, Kt, Vc);
    if (use_split) {
        k_attn<<<512, 512, 0, stream>>>(Qt, Kt, Vc, Opart);
        k_comb<<<BB * (NN / 32), 256, 0, stream>>>(Opart, mri, cwb, Xb);
    } else {
        k_attn_fb<<<BB * (NN / QW), 512, 0, stream>>>(Qt, Kt, Vc, mri, cwb, Xb);
    }
    k_conv3<<<256, 512, 0, stream>>>(Xb, Wb, c1b, Yb);
    k_out<<<256, 256, 0, stream>>>(Yb, w2p, b2p, out);
}

// Round 17
// 116.727 us; speedup vs baseline: 1.3068x; 1.3068x over previous
//
#include <hip/hip_runtime.h>
#include <hip/hip_bf16.h>
#include <math.h>

#define BB 2
#define CC 128
#define CHH 64
#define DD 16
#define NN 4096   // 16*16*16
#define SP 256    // 16*16
#define KTOT 3456 // 27*128
#define NKS 8     // key slices for split-K attention

typedef float  f32x4 __attribute__((ext_vector_type(4)));
typedef short  s16x4 __attribute__((ext_vector_type(4)));
typedef short  s16x8 __attribute__((ext_vector_type(8)));

static __device__ __forceinline__ unsigned short f2bf(float x) {
    __hip_bfloat16 h = __float2bfloat16(x);
    return __builtin_bit_cast(unsigned short, h);
}

// ---------------- K0: weight prep ----------------
__global__ __launch_bounds__(256) void k_prep(const float* __restrict__ c1w, const float* __restrict__ c2w,
                                              const float* __restrict__ bg, const float* __restrict__ bbeta,
                                              const float* __restrict__ bm, const float* __restrict__ bv,
                                              const float* __restrict__ c2b,
                                              const float* __restrict__ qw, const float* __restrict__ kw,
                                              const float* __restrict__ vw,
                                              unsigned short* __restrict__ Wb,
                                              unsigned short* __restrict__ w2p,
                                              float* __restrict__ b2p,
                                              unsigned short* __restrict__ qwb,
                                              unsigned short* __restrict__ kwb,
                                              unsigned short* __restrict__ vwb) {
    int idx = blockIdx.x * 256 + threadIdx.x;
    for (int e = idx; e < CHH * KTOT; e += gridDim.x * 256) {
        int h = e / KTOT, rem = e % KTOT, tap = rem >> 7, c = rem & 127;
        Wb[e] = f2bf(c1w[(h * CC + c) * 27 + tap]);
    }
    for (int e = idx; e < CC * CC; e += gridDim.x * 256) {
        qwb[e] = f2bf(qw[e]);
        kwb[e] = f2bf(kw[e]);
        vwb[e] = f2bf(vw[e]);
    }
    for (int e = idx; e < CC * CHH; e += gridDim.x * 256) {
        int h = e & 63;
        float iv = rsqrtf(bv[h] + 1e-5f);
        w2p[e] = f2bf(c2w[e] * bg[h] * iv);
    }
    if (idx < CC) {
        float s = c2b[idx];
        for (int h = 0; h < CHH; h++) {
            float iv = rsqrtf(bv[h] + 1e-5f);
            s += c2w[idx * CHH + h] * (bbeta[h] - bm[h] * bg[h] * iv);
        }
        b2p[idx] = s;
    }
}

// ---------------- K1: pooled = mean over spatial of (mri+pet), per (b,c) ----------------
__global__ __launch_bounds__(256) void k_pool(const float* __restrict__ mri,
                                              const float* __restrict__ pet,
                                              float* __restrict__ pooled) {
    int bc = blockIdx.x;
    const float* m = mri + (size_t)bc * NN;
    const float* p = pet + (size_t)bc * NN;
    float s = 0.f;
    for (int i = threadIdx.x; i < NN; i += 256) s += m[i] + p[i];
    __shared__ float red[256];
    red[threadIdx.x] = s;
    __syncthreads();
    for (int off = 128; off > 0; off >>= 1) {
        if (threadIdx.x < off) red[threadIdx.x] += red[threadIdx.x + off];
        __syncthreads();
    }
    if (threadIdx.x == 0) pooled[bc] = red[0] * (1.0f / NN);
}

// ---------------- K2: channel attention MLP -> cw (B,C) ----------------
__global__ __launch_bounds__(128) void k_cw(const float* __restrict__ pooled,
                                            const float* __restrict__ w1, const float* __restrict__ b1,
                                            const float* __restrict__ w2, const float* __restrict__ b2,
                                            float* __restrict__ cw) {
    __shared__ float pl[BB * CC];
    __shared__ float tl[BB * CHH];
    int t = threadIdx.x;
    pl[t] = pooled[t];
    pl[t + 128] = pooled[t + 128];
    __syncthreads();
    {
        int b = t >> 6, h = t & 63;
        float acc = b1[h];
        for (int c = 0; c < CC; c++) acc += pl[b * CC + c] * w1[h * CC + c];
        tl[b * CHH + h] = fmaxf(acc, 0.f);
    }
    __syncthreads();
    for (int b = 0; b < BB; b++) {
        float acc = b2[t];
        for (int h = 0; h < CHH; h++) acc += tl[b * CHH + h] * w2[t * CHH + h];
        cw[b * CC + t] = 1.f / (1.f + __expf(-acc));
    }
}

// ---------------- K3: Q/K/V 1x1 convs via MFMA; bf16 outputs ----------------
// Qt, Kt: (b, n, c) bf16 ; Vc: (b, c, n) bf16   (replay-proven layouts)
__global__ __launch_bounds__(256) void k_qkv(const float* __restrict__ mri, const float* __restrict__ pet,
                                             const float* __restrict__ cw,
                                             const unsigned short* __restrict__ qwb, const float* __restrict__ qb,
                                             const unsigned short* __restrict__ kwb, const float* __restrict__ kb,
                                             const unsigned short* __restrict__ vwb, const float* __restrict__ vb,
                                             unsigned short* __restrict__ Qt, unsigned short* __restrict__ Kt,
                                             unsigned short* __restrict__ Vc) {
    __shared__ unsigned short am[32][136];
    __shared__ unsigned short ap[32][136];
    int blk = blockIdx.x;          // 256
    int b = blk >> 7;
    int n0 = (blk & 127) * 32;
    int t = threadIdx.x;
    for (int e = t; e < 64 * 32; e += 256) {
        int c2 = (e >> 5) << 1, j = e & 31;
        float cw0 = cw[b * CC + c2], cw1 = cw[b * CC + c2 + 1];
        size_t g0 = (size_t)(b * CC + c2) * NN + n0 + j;
        unsigned int pm = (unsigned int)f2bf(mri[g0] * cw0) | ((unsigned int)f2bf(mri[g0 + NN] * cw1) << 16);
        unsigned int pp = (unsigned int)f2bf(pet[g0] * cw0) | ((unsigned int)f2bf(pet[g0 + NN] * cw1) << 16);
        *(unsigned int*)&am[j][c2] = pm;
        *(unsigned int*)&ap[j][c2] = pp;
    }
    __syncthreads();
    int wv = t >> 6, lane = t & 63;
    int lrow = lane & 15, lg = lane >> 4;
    int o0 = wv * 32;

    s16x8 bf[2][4];
    s16x8 wf[2][4];
    f32x4 acc[2][2];

#define QKV_MAT(WPTR, BIAS, ACT)                                                            \
    {                                                                                       \
        _Pragma("unroll")                                                                   \
        for (int nt = 0; nt < 2; nt++)                                                      \
            _Pragma("unroll")                                                               \
            for (int ks = 0; ks < 4; ks++)                                                  \
                bf[nt][ks] = *(const s16x8*)&ACT[nt * 16 + lrow][ks * 32 + lg * 8];         \
        _Pragma("unroll")                                                                   \
        for (int m = 0; m < 2; m++)                                                         \
            _Pragma("unroll")                                                               \
            for (int ks = 0; ks < 4; ks++)                                                  \
                wf[m][ks] = *(const s16x8*)&WPTR[(size_t)(o0 + m * 16 + lrow) * CC + ks * 32 + lg * 8]; \
        _Pragma("unroll")                                                                   \
        for (int m = 0; m < 2; m++) {                                                       \
            float b0 = BIAS[o0 + m * 16 + lg * 4 + 0];                                      \
            float b1 = BIAS[o0 + m * 16 + lg * 4 + 1];                                      \
            float b2v = BIAS[o0 + m * 16 + lg * 4 + 2];                                     \
            float b3 = BIAS[o0 + m * 16 + lg * 4 + 3];                                      \
            _Pragma("unroll")                                                               \
            for (int nt = 0; nt < 2; nt++) {                                                \
                acc[m][nt] = (f32x4){b0, b1, b2v, b3};                                      \
                _Pragma("unroll")                                                           \
                for (int ks = 0; ks < 4; ks++)                                              \
                    acc[m][nt] = __builtin_amdgcn_mfma_f32_16x16x32_bf16(wf[m][ks], bf[nt][ks], acc[m][nt], 0, 0, 0); \
            }                                                                               \
        }                                                                                   \
    }

    QKV_MAT(qwb, qb, am);
#pragma unroll
    for (int m = 0; m < 2; m++)
#pragma unroll
        for (int nt = 0; nt < 2; nt++) {
            s16x4 q4;
#pragma unroll
            for (int r = 0; r < 4; r++) q4[r] = (short)f2bf(acc[m][nt][r]);
            *(s16x4*)&Qt[((size_t)b * NN + n0 + nt * 16 + lrow) * CC + o0 + m * 16 + lg * 4] = q4;
        }
    QKV_MAT(kwb, kb, ap);
#pragma unroll
    for (int m = 0; m < 2; m++)
#pragma unroll
        for (int nt = 0; nt < 2; nt++) {
            s16x4 k4;
#pragma unroll
            for (int r = 0; r < 4; r++) k4[r] = (short)f2bf(acc[m][nt][r]);
            *(s16x4*)&Kt[((size_t)b * NN + n0 + nt * 16 + lrow) * CC + o0 + m * 16 + lg * 4] = k4;
        }
    QKV_MAT(vwb, vb, ap);
#pragma unroll
    for (int m = 0; m < 2; m++)
#pragma unroll
        for (int nt = 0; nt < 2; nt++)
#pragma unroll
            for (int r = 0; r < 4; r++)
                Vc[((size_t)b * CC + o0 + m * 16 + lg * 4 + r) * NN + n0 + nt * 16 + lrow] =
                    (unsigned short)f2bf(acc[m][nt][r]);
#undef QKV_MAT
}

// ---------------- K4: MFMA attention, LDS-staged split-K v3 (round-15 proven) ----------------
// grid 256 = ks(8) x qc(16) x b(2); 512 thr = 8 waves x 32 q (one 512-key
// slice staged per block, 256 queries amortize it) + key-permuted V
// (PV A-frag = ONE bank-balanced ds_read_b128).
#define QW 32
__global__ __launch_bounds__(512) void k_attn(const unsigned short* __restrict__ Qt,
                                              const unsigned short* __restrict__ Kt,
                                              const unsigned short* __restrict__ Vc,
                                              float* __restrict__ Opart) {
    __shared__ unsigned short Ks[2][32][136];   // 17408 B
    __shared__ unsigned short Vs[2][128][40];   // 20480 B (cols 0..31 = permuted keys)
    int bid = blockIdx.x;          // 0..255
    int ks = bid & 7;              // key slice == XCD (bid%8)
    int r = bid >> 3;              // 0..31
    int qc = r >> 1;               // 0..15
    int b = r & 1;
    int t = threadIdx.x;           // 0..511
    int wv = t >> 6;               // 0..7
    int lane = t & 63;
    int lrow = lane & 15;
    int lg = lane >> 4;
    int q0 = qc * 256 + wv * 32;

    const unsigned short* Qb = Qt + (size_t)b * NN * CC;
    const unsigned short* Kb = Kt + (size_t)b * NN * CC;
    const unsigned short* Vb = Vc + (size_t)b * CC * NN;

    // stage (512 thr): K = 512 b128 units (1/thread); V = 1024 b64 units
    // (2/thread), key k -> in-row pos 8*((k&15)>>2) + (k&3) + 4*(k>>4).
#define STAGE(BUF, K0)                                                                      \
    {                                                                                       \
        {                                                                                   \
            int row = t >> 4, seg = t & 15;                                                 \
            *(s16x8*)&Ks[BUF][row][seg * 8] =                                               \
                *(const s16x8*)(Kb + (size_t)((K0) + row) * CC + seg * 8);                  \
        }                                                                                   \
        _Pragma("unroll")                                                                   \
        for (int e2 = 0; e2 < 2; e2++) {                                                    \
            int e = t + e2 * 512; int c = e >> 3, m = e & 7;                                \
            *(s16x4*)&Vs[BUF][c][8 * (m & 3) + 4 * (m >> 2)] =                              \
                *(const s16x4*)(Vb + (size_t)c * NN + (K0) + 4 * m);                        \
        }                                                                                   \
    }

    s16x8 qf[2][4];
#pragma unroll
    for (int qt = 0; qt < 2; qt++)
#pragma unroll
        for (int cc = 0; cc < 4; cc++)
            qf[qt][cc] = *(const s16x8*)(Qb + (size_t)(q0 + qt * 16 + lrow) * CC + cc * 32 + lg * 8);

    f32x4 acc[2][8];
#pragma unroll
    for (int qt = 0; qt < 2; qt++)
#pragma unroll
        for (int ct = 0; ct < 8; ct++) acc[qt][ct] = (f32x4){0.f, 0.f, 0.f, 0.f};

    int kbase = ks * 512;
    STAGE(0, kbase);
#pragma unroll 1
    for (int i = 0; i < 16; i++) {
        __syncthreads();
        if (i + 1 < 16) STAGE((i + 1) & 1, kbase + (i + 1) * 32);
        int cur = i & 1;
        f32x4 sc[2][2];
#pragma unroll
        for (int kt = 0; kt < 2; kt++) {
            s16x8 kf[4];
#pragma unroll
            for (int cc = 0; cc < 4; cc++)
                kf[cc] = *(const s16x8*)&Ks[cur][kt * 16 + lrow][cc * 32 + lg * 8];
#pragma unroll
            for (int qt = 0; qt < 2; qt++) {
                f32x4 a = (f32x4){0.f, 0.f, 0.f, 0.f};
#pragma unroll
                for (int cc = 0; cc < 4; cc++)
                    a = __builtin_amdgcn_mfma_f32_16x16x32_bf16(kf[cc], qf[qt][cc], a, 0, 0, 0);
                sc[qt][kt] = a;
            }
        }
        s16x8 pf[2];
#pragma unroll
        for (int qt = 0; qt < 2; qt++) {
#pragma unroll
            for (int kt = 0; kt < 2; kt++) {
                f32x4 s = sc[qt][kt];
                float m = fmaxf(fmaxf(s[0], s[1]), fmaxf(s[2], s[3]));
                m = fmaxf(m, __shfl_xor(m, 16));
                m = fmaxf(m, __shfl_xor(m, 32));
                float e0 = __expf(s[0] - m), e1 = __expf(s[1] - m);
                float e2 = __expf(s[2] - m), e3 = __expf(s[3] - m);
                float sum = e0 + e1 + e2 + e3;
                sum += __shfl_xor(sum, 16);
                sum += __shfl_xor(sum, 32);
                float inv = 1.0f / sum;
                pf[qt][kt * 4 + 0] = (short)f2bf(e0 * inv);
                pf[qt][kt * 4 + 1] = (short)f2bf(e1 * inv);
                pf[qt][kt * 4 + 2] = (short)f2bf(e2 * inv);
                pf[qt][kt * 4 + 3] = (short)f2bf(e3 * inv);
            }
        }
        // PV: one bank-balanced b128 per ct (permuted layout = A-frag order)
#pragma unroll
        for (int ct = 0; ct < 8; ct++) {
            s16x8 vf = *(const s16x8*)&Vs[cur][ct * 16 + lrow][8 * lg];
            acc[0][ct] = __builtin_amdgcn_mfma_f32_16x16x32_bf16(vf, pf[0], acc[0][ct], 0, 0, 0);
            acc[1][ct] = __builtin_amdgcn_mfma_f32_16x16x32_bf16(vf, pf[1], acc[1][ct], 0, 0, 0);
        }
    }
#undef STAGE
    float* Op = Opart + ((size_t)(ks * BB + b) * NN) * CC;
#pragma unroll
    for (int qt = 0; qt < 2; qt++)
#pragma unroll
        for (int ct = 0; ct < 8; ct++)
            *(f32x4*)&Op[(size_t)(q0 + qt * 16 + lrow) * CC + ct * 16 + lg * 4] = acc[qt][ct];
}

// ---------------- K4b: combine 8 slice-partials + mri*cw -> Xb (b,n,c) bf16 ----------------
__global__ __launch_bounds__(256) void k_comb(const float* __restrict__ Opart,
                                              const float* __restrict__ mri, const float* __restrict__ cw,
                                              unsigned short* __restrict__ Xb) {
    __shared__ float tl[128][33];
    __shared__ float cws[128];
    int bid = blockIdx.x;             // 256 = b*128 + nb
    int b = bid >> 7, n0 = (bid & 127) * 32;
    int t = threadIdx.x;
    if (t < 128) cws[t] = cw[b * CC + t];
    {
        int c = t >> 1, half = t & 1;
        const float* src = mri + (size_t)(b * CC + c) * NN + n0 + half * 16;
#pragma unroll
        for (int j = 0; j < 4; j++) {
            f32x4 v = *(const f32x4*)(src + j * 4);
            tl[c][half * 16 + j * 4 + 0] = v[0];
            tl[c][half * 16 + j * 4 + 1] = v[1];
            tl[c][half * 16 + j * 4 + 2] = v[2];
            tl[c][half * 16 + j * 4 + 3] = v[3];
        }
    }
    __syncthreads();
    {
        int n = t >> 3, c0 = (t & 7) * 16;
        size_t rowoff = (size_t)(n0 + n) * CC + c0;
        s16x8 o0v, o1v;
#pragma unroll
        for (int ci = 0; ci < 4; ci++) {
            f32x4 s = (f32x4){0.f, 0.f, 0.f, 0.f};
#pragma unroll
            for (int ks = 0; ks < NKS; ks++) {
                f32x4 p = *(const f32x4*)&Opart[((size_t)(ks * BB + b) * NN) * CC + rowoff + ci * 4];
                s[0] += p[0]; s[1] += p[1]; s[2] += p[2]; s[3] += p[3];
            }
#pragma unroll
            for (int j = 0; j < 4; j++) {
                int c = c0 + ci * 4 + j;
                float v = s[j] + tl[c][n] * cws[c];
                if (ci < 2) o0v[ci * 4 + j] = (short)f2bf(v);
                else        o1v[(ci - 2) * 4 + j] = (short)f2bf(v);
            }
        }
        unsigned short* dst = Xb + ((size_t)b * NN + n0 + n) * CC + c0;
        *(s16x8*)dst = o0v;
        *(s16x8*)(dst + 8) = o1v;
    }
}

// ---------------- K4-fallback: round-10 attention (if ws too small for Opart) ----------------
__global__ __launch_bounds__(512) void k_attn_fb(const unsigned short* __restrict__ Qt,
                                                 const unsigned short* __restrict__ Kt,
                                                 const unsigned short* __restrict__ Vc,
                                                 const float* __restrict__ mri, const float* __restrict__ cw,
                                                 unsigned short* __restrict__ Xb) {
    __shared__ float Op[8][16][68];
    int bid = blockIdx.x;
    int lid = (bid & 7) * 32 + (bid >> 3);
    int b = lid >> 7;
    int q0 = (lid & 127) * QW;
    int t = threadIdx.x;
    int wv = t >> 6;
    int lane = t & 63;
    int lrow = lane & 15;
    int lg = lane >> 4;

    const unsigned short* Qb = Qt + (size_t)b * NN * CC;
    const unsigned short* Kb = Kt + (size_t)b * NN * CC;
    const unsigned short* Vb = Vc + (size_t)b * CC * NN;

    s16x8 qf[2][4];
#pragma unroll
    for (int qt = 0; qt < 2; qt++)
#pragma unroll
        for (int cc = 0; cc < 4; cc++)
            qf[qt][cc] = *(const s16x8*)(Qb + (size_t)(q0 + qt * 16 + lrow) * CC + cc * 32 + lg * 8);

    f32x4 acc[2][8];
#pragma unroll
    for (int qt = 0; qt < 2; qt++)
#pragma unroll
        for (int ct = 0; ct < 8; ct++) acc[qt][ct] = (f32x4){0.f, 0.f, 0.f, 0.f};

    for (int kg = wv; kg < 128; kg += 8) {
        int k0 = kg * 32;
        f32x4 sc[2][2];
#pragma unroll
        for (int kt = 0; kt < 2; kt++) {
            s16x8 kf[4];
#pragma unroll
            for (int cc = 0; cc < 4; cc++)
                kf[cc] = *(const s16x8*)(Kb + (size_t)(k0 + kt * 16 + lrow) * CC + cc * 32 + lg * 8);
#pragma unroll
            for (int qt = 0; qt < 2; qt++) {
                f32x4 a = (f32x4){0.f, 0.f, 0.f, 0.f};
#pragma unroll
                for (int cc = 0; cc < 4; cc++)
                    a = __builtin_amdgcn_mfma_f32_16x16x32_bf16(kf[cc], qf[qt][cc], a, 0, 0, 0);
                sc[qt][kt] = a;
            }
        }
        s16x8 pf[2];
#pragma unroll
        for (int qt = 0; qt < 2; qt++) {
#pragma unroll
            for (int kt = 0; kt < 2; kt++) {
                f32x4 s = sc[qt][kt];
                float m = fmaxf(fmaxf(s[0], s[1]), fmaxf(s[2], s[3]));
                m = fmaxf(m, __shfl_xor(m, 16));
                m = fmaxf(m, __shfl_xor(m, 32));
                float e0 = __expf(s[0] - m), e1 = __expf(s[1] - m);
                float e2 = __expf(s[2] - m), e3 = __expf(s[3] - m);
                float sum = e0 + e1 + e2 + e3;
                sum += __shfl_xor(sum, 16);
                sum += __shfl_xor(sum, 32);
                float inv = 1.0f / sum;
                pf[qt][kt * 4 + 0] = (short)f2bf(e0 * inv);
                pf[qt][kt * 4 + 1] = (short)f2bf(e1 * inv);
                pf[qt][kt * 4 + 2] = (short)f2bf(e2 * inv);
                pf[qt][kt * 4 + 3] = (short)f2bf(e3 * inv);
            }
        }
#pragma unroll
        for (int ct = 0; ct < 8; ct++) {
            const unsigned short* vp = Vb + (size_t)(ct * 16 + lrow) * NN + k0 + 4 * lg;
            s16x4 v0 = *(const s16x4*)vp;
            s16x4 v1 = *(const s16x4*)(vp + 16);
            s16x8 vf = (s16x8){v0[0], v0[1], v0[2], v0[3], v1[0], v1[1], v1[2], v1[3]};
            acc[0][ct] = __builtin_amdgcn_mfma_f32_16x16x32_bf16(vf, pf[0], acc[0][ct], 0, 0, 0);
            acc[1][ct] = __builtin_amdgcn_mfma_f32_16x16x32_bf16(vf, pf[1], acc[1][ct], 0, 0, 0);
        }
    }
#pragma unroll
    for (int p = 0; p < 4; p++) {
        int qt = p >> 1, ch = p & 1;
#pragma unroll
        for (int ci = 0; ci < 4; ci++)
            *(f32x4*)&Op[wv][lrow][ci * 16 + lg * 4] = acc[qt][ch * 4 + ci];
        __syncthreads();
#pragma unroll
        for (int rep = 0; rep < 2; rep++) {
            int e = t + rep * 512;
            int cl = e & 63, q = e >> 6;
            int c = ch * 64 + cl;
            float s = 0.f;
#pragma unroll
            for (int w = 0; w < 8; w++) s += Op[w][q][cl];
            int n = q0 + qt * 16 + q;
            size_t gi = ((size_t)b * CC + c) * NN + n;
            Xb[((size_t)b * NN + n) * CC + c] = f2bf(s + mri[gi] * cw[b * CC + c]);
        }
        __syncthreads();
    }
}

// ---------------- K5: 3x3x3 conv, LDS-staged implicit-GEMM MFMA + bias + ReLU ----------------
__global__ __launch_bounds__(512) void k_conv3(const unsigned short* __restrict__ Xb,
                                               const unsigned short* __restrict__ Wb,
                                               const float* __restrict__ c1b,
                                               unsigned short* __restrict__ Yb) {
    __shared__ unsigned short Xs[3][4][18][136];  // 58752 B  (w shifted +1, OOB zero)
    __shared__ unsigned short Ws[2][64][136];     // 34816 B  (cols 0..127 used)
    int bid = blockIdx.x;             // 256 = b*128 + d*8 + hq
    int b = bid >> 7;
    int d = (bid >> 3) & 15;
    int hp = (bid & 7) * 2;
    int t = threadIdx.x;
    int wv = t >> 6;
    int lane = t & 63;
    int lrow = lane & 15, lg = lane >> 4;
    int mt = wv >> 1;        // ch tile 0..3
    int nt = wv & 1;         // h row 0..1

    const unsigned short* Xbase = Xb + (size_t)b * NN * CC;

    {
        unsigned short* xz = &Xs[0][0][0][0];
        const s16x8 z8 = (s16x8){0, 0, 0, 0, 0, 0, 0, 0};
        for (int e = t; e < (3 * 4 * 18 * 136) / 8; e += 512)
            *(s16x8*)(xz + e * 8) = z8;
    }
    __syncthreads();
    for (int e = t; e < 3 * 4 * 16 * 16; e += 512) {
        int seg = e & 15;
        int w = (e >> 4) & 15;
        int sh = (e >> 8) & 3;
        int sd = e >> 10;
        int dd2 = d - 1 + sd, hh2 = hp - 1 + sh;
        if ((unsigned)dd2 < 16u && (unsigned)hh2 < 16u) {
            int n = dd2 * 256 + hh2 * 16 + w;
            *(s16x8*)&Xs[sd][sh][w + 1][seg * 8] = *(const s16x8*)(Xbase + (size_t)n * CC + seg * 8);
        }
    }

#define WSTAGE(BUF, TAP)                                                       \
    for (int e = t; e < 1024; e += 512) {                                      \
        int row = e >> 4, seg = e & 15;                                        \
        *(s16x8*)&Ws[BUF][row][seg * 8] =                                      \
            *(const s16x8*)(Wb + (size_t)row * KTOT + (TAP) * 128 + seg * 8);  \
    }
    WSTAGE(0, 0);

    f32x4 acc = (f32x4){0.f, 0.f, 0.f, 0.f};
#pragma unroll 1
    for (int tap = 0; tap < 27; tap++) {
        __syncthreads();
        if (tap + 1 < 27) { WSTAGE((tap + 1) & 1, tap + 1); }
        int cur = tap & 1;
        int kd = tap / 9;
        int rem = tap - kd * 9;
        int kh = rem / 3;
        int kw = rem - kh * 3;
#pragma unroll
        for (int cc = 0; cc < 4; cc++) {
            s16x8 af = *(const s16x8*)&Ws[cur][mt * 16 + lrow][cc * 32 + lg * 8];
            s16x8 bfv = *(const s16x8*)&Xs[kd][nt + kh][lrow + kw][cc * 32 + lg * 8];
            acc = __builtin_amdgcn_mfma_f32_16x16x32_bf16(af, bfv, acc, 0, 0, 0);
        }
    }
#undef WSTAGE
    int ch0 = mt * 16 + lg * 4;
    int n = d * 256 + (hp + nt) * 16 + lrow;
    s16x4 yv;
#pragma unroll
    for (int r = 0; r < 4; r++) {
        float y = fmaxf(acc[r] + c1b[ch0 + r], 0.f);
        yv[r] = (short)f2bf(y);
    }
    *(s16x4*)&Yb[((size_t)b * NN + n) * CHH + ch0] = yv;
}

// ---------------- K6: final 1x1 conv (CH->C) via MFMA, BN pre-folded ----------------
__global__ __launch_bounds__(256) void k_out(const unsigned short* __restrict__ Yb,
                                             const unsigned short* __restrict__ w2p,
                                             const float* __restrict__ b2p,
                                             float* __restrict__ out) {
    int bid = blockIdx.x;    // 256
    int b = bid >> 7, n0 = (bid & 127) * 32;
    int t = threadIdx.x;
    int wv = t >> 6, lane = t & 63;
    int lrow = lane & 15, lg = lane >> 4;
    int o0 = wv * 32;

    f32x4 acc[2][2];
#pragma unroll
    for (int m = 0; m < 2; m++)
#pragma unroll
        for (int nt = 0; nt < 2; nt++) acc[m][nt] = (f32x4){0.f, 0.f, 0.f, 0.f};

#pragma unroll
    for (int ks = 0; ks < 2; ks++) {
        s16x8 a0 = *(const s16x8*)&w2p[(o0 + lrow) * CHH + ks * 32 + lg * 8];
        s16x8 a1 = *(const s16x8*)&w2p[(o0 + 16 + lrow) * CHH + ks * 32 + lg * 8];
        s16x8 f0 = *(const s16x8*)&Yb[((size_t)b * NN + n0 + lrow) * CHH + ks * 32 + lg * 8];
        s16x8 f1 = *(const s16x8*)&Yb[((size_t)b * NN + n0 + 16 + lrow) * CHH + ks * 32 + lg * 8];
        acc[0][0] = __builtin_amdgcn_mfma_f32_16x16x32_bf16(a0, f0, acc[0][0], 0, 0, 0);
        acc[0][1] = __builtin_amdgcn_mfma_f32_16x16x32_bf16(a0, f1, acc[0][1], 0, 0, 0);
        acc[1][0] = __builtin_amdgcn_mfma_f32_16x16x32_bf16(a1, f0, acc[1][0], 0, 0, 0);
        acc[1][1] = __builtin_amdgcn_mfma_f32_16x16x32_bf16(a1, f1, acc[1][1], 0, 0, 0);
    }
#pragma unroll
    for (int m = 0; m < 2; m++) {
#pragma unroll
        for (int r = 0; r < 4; r++) {
            int o = o0 + m * 16 + lg * 4 + r;
            float bias = b2p[o];
#pragma unroll
            for (int nt = 0; nt < 2; nt++) {
                int n = n0 + nt * 16 + lrow;
                out[((size_t)b * CC + o) * NN + n] = acc[m][nt][r] + bias;
            }
        }
    }
}

extern "C" void kernel_launch(void* const* d_in, const int* in_sizes, int n_in,
                              void* d_out, int out_size, void* d_ws, size_t ws_size,
                              hipStream_t stream) {
    const float* mri = (const float*)d_in[0];
    const float* pet = (const float*)d_in[1];
    const float* qw  = (const float*)d_in[2];
    const float* qb  = (const float*)d_in[3];
    const float* kw  = (const float*)d_in[4];
    const float* kb  = (const float*)d_in[5];
    const float* vw  = (const float*)d_in[6];
    const float* vb  = (const float*)d_in[7];
    const float* w1  = (const float*)d_in[8];
    const float* b1  = (const float*)d_in[9];
    const float* w2  = (const float*)d_in[10];
    const float* b2  = (const float*)d_in[11];
    const float* c1w = (const float*)d_in[12];
    const float* c1b = (const float*)d_in[13];
    const float* bg  = (const float*)d_in[14];
    const float* bbeta = (const float*)d_in[15];
    const float* bm  = (const float*)d_in[16];
    const float* bv  = (const float*)d_in[17];
    const float* c2w = (const float*)d_in[18];
    const float* c2b = (const float*)d_in[19];
    float* out = (float*)d_out;

    float* ws = (float*)d_ws;
    float* pooled = ws;                               // 256 f32
    float* cwb    = ws + 256;                         // 256 f32
    float* b2p    = ws + 512;                         // 128 f32
    unsigned short* Qt  = (unsigned short*)(ws + 1024);
    unsigned short* Kt  = Qt + (size_t)BB * NN * CC;
    unsigned short* Vc  = Kt + (size_t)BB * NN * CC;
    unsigned short* Xb  = Vc + (size_t)BB * NN * CC;  // (b,n,c) bf16
    unsigned short* Yb  = Xb + (size_t)BB * NN * CC;  // (b,n,h) bf16
    unsigned short* Wb  = Yb + (size_t)BB * NN * CHH; // 64*3456 bf16
    unsigned short* w2p = Wb + (size_t)CHH * KTOT;    // 128*64 bf16
    unsigned short* qwb = w2p + (size_t)CC * CHH;     // 128*128 bf16
    unsigned short* kwb = qwb + (size_t)CC * CC;
    unsigned short* vwb = kwb + (size_t)CC * CC;
    // 16B-align Opart
    size_t head_bytes = (size_t)((char*)(vwb + (size_t)CC * CC) - (char*)d_ws);
    head_bytes = (head_bytes + 15) & ~(size_t)15;
    float* Opart = (float*)((char*)d_ws + head_bytes);
    size_t opart_bytes = (size_t)NKS * BB * NN * CC * sizeof(float);   // 32 MB
    bool use_split = (head_bytes + opart_bytes) <= ws_size;

    k_prep<<<64, 256, 0, stream>>>(c1w, c2w, bg, bbeta, bm, bv, c2b, qw, kw, vw,
                                   Wb, w2p, b2p, qwb, kwb, vwb);
    k_pool<<<BB * CC, 256, 0, stream>>>(mri, pet, pooled);
    k_cw<<<1, 128, 0, stream>>>(pooled, w1, b1, w2, b2, cwb);
    k_qkv<<<BB * (NN / 32), 256, 0, stream>>>(mri, pet, cwb, qwb, qb, kwb, kb, vwb, vb, Qt, Kt, Vc);
    if (use_split) {
        k_attn<<<256, 512, 0, stream>>>(Qt, Kt, Vc, Opart);
        k_comb<<<BB * (NN / 32), 256, 0, stream>>>(Opart, mri, cwb, Xb);
    } else {
        k_attn_fb<<<BB * (NN / QW), 512, 0, stream>>>(Qt, Kt, Vc, mri, cwb, Xb);
    }
    k_conv3<<<256, 512, 0, stream>>>(Xb, Wb, c1b, Yb);
    k_out<<<256, 256, 0, stream>>>(Yb, w2p, b2p, out);
}